// Round 2
// baseline (665.117 us; speedup 1.0000x reference)
//
#include <hip/hip_runtime.h>
#include <stdint.h>

typedef unsigned short u16;
typedef __attribute__((ext_vector_type(8))) short short8;   // 8 x bf16 (4 VGPRs)
typedef __attribute__((ext_vector_type(4))) float f32x4;
typedef __attribute__((ext_vector_type(4))) unsigned short u16x4;

#define DMODEL 1024
#define SEQ    2048
#define BATCH  4
#define NHEAD  16
#define DH     64
#define NTOK   (BATCH*SEQ)
#define EPS    1e-5f

__device__ __forceinline__ float bf2f(u16 u){
  union { unsigned int u; float f; } x; x.u = ((unsigned int)u)<<16; return x.f;
}
__device__ __forceinline__ u16 f2bf(float f){
  union { float f; unsigned int u; } x; x.f = f;
  unsigned int r = x.u + 0x7FFFu + ((x.u>>16)&1u);
  return (u16)(r>>16);
}
// split f32 -> hi bf16 + lo bf16 (residual), combined rel err ~2^-18
__device__ __forceinline__ void split8(const float* v, short8& hi, short8& lo){
  #pragma unroll
  for (int j=0;j<8;++j){
    u16 h = f2bf(v[j]);
    float r = v[j] - bf2f(h);
    hi[j] = (short)h;
    lo[j] = (short)f2bf(r);
  }
}

__device__ __forceinline__ void gload_lds16(const void* g, void* l){
  __builtin_amdgcn_global_load_lds((__attribute__((address_space(1))) unsigned int*)g,
                                   (__attribute__((address_space(3))) unsigned int*)l,
                                   16, 0, 0);
}

// ---------------- weight fp32 -> bf16 convert ----------------
__global__ __launch_bounds__(256) void cvt_f32_bf16(const float* __restrict__ src,
                                                    u16* __restrict__ dst, int n){
  int i = (blockIdx.x*256 + threadIdx.x)*4;
  if (i < n){
    float4 v = *reinterpret_cast<const float4*>(src + i);
    u16x4 o; o.x = f2bf(v.x); o.y = f2bf(v.y); o.z = f2bf(v.z); o.w = f2bf(v.w);
    *reinterpret_cast<u16x4*>(dst + i) = o;
  }
}

// ---------------- LayerNorm (optionally residual in1), writes f32 (opt) + bf16 (opt) ----------------
__global__ __launch_bounds__(256) void ln_kernel(const float* __restrict__ in0,
                                                 const float* __restrict__ in1,
                                                 const float* __restrict__ sc,
                                                 const float* __restrict__ bi,
                                                 float* __restrict__ of32,
                                                 u16* __restrict__ obf){
  int row = blockIdx.x;
  int t = threadIdx.x;
  size_t base = (size_t)row*DMODEL + t*4;
  float4 v = *reinterpret_cast<const float4*>(in0 + base);
  if (in1){
    float4 a = *reinterpret_cast<const float4*>(in1 + base);
    v.x += a.x; v.y += a.y; v.z += a.z; v.w += a.w;
  }
  float s  = v.x+v.y+v.z+v.w;
  float ss = v.x*v.x+v.y*v.y+v.z*v.z+v.w*v.w;
  #pragma unroll
  for (int m=1;m<64;m<<=1){ s += __shfl_xor(s,m); ss += __shfl_xor(ss,m); }
  __shared__ float rs_[4], rss_[4];
  int w = t>>6, l = t&63;
  if (l==0){ rs_[w]=s; rss_[w]=ss; }
  __syncthreads();
  s  = rs_[0]+rs_[1]+rs_[2]+rs_[3];
  ss = rss_[0]+rss_[1]+rss_[2]+rss_[3];
  float mu  = s * (1.0f/DMODEL);
  float var = ss * (1.0f/DMODEL) - mu*mu;
  var = fmaxf(var, 0.0f);
  float r = rsqrtf(var + EPS);
  float4 g = *reinterpret_cast<const float4*>(sc + t*4);
  float4 b = *reinterpret_cast<const float4*>(bi + t*4);
  float o0 = (v.x-mu)*r*g.x + b.x;
  float o1 = (v.y-mu)*r*g.y + b.y;
  float o2 = (v.z-mu)*r*g.z + b.z;
  float o3 = (v.w-mu)*r*g.w + b.w;
  if (of32){
    float4 ov; ov.x=o0; ov.y=o1; ov.z=o2; ov.w=o3;
    *reinterpret_cast<float4*>(of32 + base) = ov;
  }
  if (obf){
    u16x4 ob; ob.x=f2bf(o0); ob.y=f2bf(o1); ob.z=f2bf(o2); ob.w=f2bf(o3);
    *reinterpret_cast<u16x4*>(obf + base) = ob;
  }
}

// ---------------- split-precision QKV GEMM ----------------
// C[M][3072] = A[M][K]_f32 @ Wsel[1024][K]_f32^T using bf16 hi/lo split (3 MFMAs).
// 128x128 tile, BK=32, 4 waves (2x2). Reg-staged LDS with XOR chunk swizzle.
__global__ __launch_bounds__(256) void gemm_qkv_split(const float* __restrict__ A,
                                                      const float* __restrict__ Wq,
                                                      const float* __restrict__ Wk,
                                                      const float* __restrict__ Wv,
                                                      float* __restrict__ C,
                                                      int M, int N, int K){
  __shared__ u16 Ah[128*32], Al[128*32], Bh[128*32], Bl[128*32];
  int t = threadIdx.x, l = t&63, w = t>>6;
  int bm = blockIdx.y, bn = blockIdx.x;
  int wr = w>>1, wc = w&1;
  const float* Wsel = (bn < 8) ? Wq : (bn < 16 ? Wk : Wv);
  int bnl = bn & 7;

  f32x4 acc[4][4];
  #pragma unroll
  for (int m=0;m<4;++m)
    #pragma unroll
    for (int n=0;n<4;++n)
      #pragma unroll
      for (int i=0;i<4;++i) acc[m][n][i] = 0.0f;

  int r = t>>1, half = t&1;
  const int nk = K/32;
  for (int kt=0; kt<nk; ++kt){
    int k0 = kt*32;
    __syncthreads();
    // stage A hi/lo
    {
      const float* p = A + (size_t)(bm*128 + r)*K + k0 + half*16;
      float buf[16];
      #pragma unroll
      for (int q=0;q<4;++q)
        *reinterpret_cast<float4*>(&buf[q*4]) = reinterpret_cast<const float4*>(p)[q];
      #pragma unroll
      for (int j=0;j<2;++j){
        short8 hi, lo; split8(&buf[j*8], hi, lo);
        int pc = (half*2+j) ^ (r&3);
        *reinterpret_cast<short8*>(&Ah[r*32 + pc*8]) = hi;
        *reinterpret_cast<short8*>(&Al[r*32 + pc*8]) = lo;
      }
    }
    // stage W hi/lo
    {
      const float* p = Wsel + (size_t)(bnl*128 + r)*K + k0 + half*16;
      float buf[16];
      #pragma unroll
      for (int q=0;q<4;++q)
        *reinterpret_cast<float4*>(&buf[q*4]) = reinterpret_cast<const float4*>(p)[q];
      #pragma unroll
      for (int j=0;j<2;++j){
        short8 hi, lo; split8(&buf[j*8], hi, lo);
        int pc = (half*2+j) ^ (r&3);
        *reinterpret_cast<short8*>(&Bh[r*32 + pc*8]) = hi;
        *reinterpret_cast<short8*>(&Bl[r*32 + pc*8]) = lo;
      }
    }
    __syncthreads();
    short8 ah[4], al[4], bh[4], bl[4];
    #pragma unroll
    for (int m=0;m<4;++m){
      int row = wr*64 + m*16 + (l&15);
      int cp = (l>>4) ^ (row&3);
      ah[m] = *reinterpret_cast<const short8*>(&Ah[row*32 + cp*8]);
      al[m] = *reinterpret_cast<const short8*>(&Al[row*32 + cp*8]);
    }
    #pragma unroll
    for (int n=0;n<4;++n){
      int row = wc*64 + n*16 + (l&15);
      int cp = (l>>4) ^ (row&3);
      bh[n] = *reinterpret_cast<const short8*>(&Bh[row*32 + cp*8]);
      bl[n] = *reinterpret_cast<const short8*>(&Bl[row*32 + cp*8]);
    }
    #pragma unroll
    for (int m=0;m<4;++m)
      #pragma unroll
      for (int n=0;n<4;++n){
        acc[m][n] = __builtin_amdgcn_mfma_f32_16x16x32_bf16(ah[m], bh[n], acc[m][n], 0,0,0);
        acc[m][n] = __builtin_amdgcn_mfma_f32_16x16x32_bf16(ah[m], bl[n], acc[m][n], 0,0,0);
        acc[m][n] = __builtin_amdgcn_mfma_f32_16x16x32_bf16(al[m], bh[n], acc[m][n], 0,0,0);
      }
  }

  #pragma unroll
  for (int m=0;m<4;++m){
    int row0 = bm*128 + wr*64 + m*16 + ((l>>4)<<2);
    #pragma unroll
    for (int n=0;n<4;++n){
      int col = bn*128 + wc*64 + n*16 + (l&15);
      #pragma unroll
      for (int i=0;i<4;++i)
        C[(size_t)(row0+i)*N + col] = acc[m][n][i];
    }
  }
}

// ---------------- bf16 GEMM: C[M][N] = A[M][K] @ W[N][K]^T  (m97 structure) ----------------
template<bool BIAS, bool RELU, bool RES, bool OUTF32>
__global__ __launch_bounds__(256) void gemm_bt(const u16* __restrict__ A,
                                               const u16* __restrict__ W,
                                               const float* __restrict__ bias,
                                               const float* __restrict__ resid,
                                               void* __restrict__ outp,
                                               int M, int N, int K){
  __shared__ u16 As[128*32];
  __shared__ u16 Bs[128*32];
  int t = threadIdx.x, l = t&63, w = t>>6;
  int bm = blockIdx.y, bn = blockIdx.x;
  int wr = w>>1, wc = w&1;
  f32x4 acc[4][4];
  #pragma unroll
  for (int m=0;m<4;++m)
    #pragma unroll
    for (int n=0;n<4;++n)
      #pragma unroll
      for (int i=0;i<4;++i) acc[m][n][i] = 0.0f;

  const int nk = K/32;
  for (int kt=0; kt<nk; ++kt){
    int k0 = kt*32;
    __syncthreads();
    #pragma unroll
    for (int i=0;i<2;++i){
      int idx = i*256 + t;
      int r = idx>>2;
      int cc = (idx&3) ^ (r&3);       // inverse-swizzled source chunk
      gload_lds16(A + (size_t)(bm*128 + r)*K + k0 + cc*8, &As[idx*8]);
      gload_lds16(W + (size_t)(bn*128 + r)*K + k0 + cc*8, &Bs[idx*8]);
    }
    __syncthreads();
    short8 af[4], bf[4];
    #pragma unroll
    for (int m=0;m<4;++m){
      int row = wr*64 + m*16 + (l&15);
      int cp = (l>>4) ^ (row&3);
      af[m] = *reinterpret_cast<const short8*>(&As[row*32 + cp*8]);
    }
    #pragma unroll
    for (int n=0;n<4;++n){
      int row = wc*64 + n*16 + (l&15);
      int cp = (l>>4) ^ (row&3);
      bf[n] = *reinterpret_cast<const short8*>(&Bs[row*32 + cp*8]);
    }
    #pragma unroll
    for (int m=0;m<4;++m)
      #pragma unroll
      for (int n=0;n<4;++n)
        acc[m][n] = __builtin_amdgcn_mfma_f32_16x16x32_bf16(af[m], bf[n], acc[m][n], 0,0,0);
  }

  #pragma unroll
  for (int m=0;m<4;++m){
    int row0 = bm*128 + wr*64 + m*16 + ((l>>4)<<2);
    #pragma unroll
    for (int n=0;n<4;++n){
      int col = bn*128 + wc*64 + n*16 + (l&15);
      float bv = BIAS ? bias[col] : 0.0f;
      #pragma unroll
      for (int i=0;i<4;++i){
        float vv = acc[m][n][i] + bv;
        if (RELU) vv = fmaxf(vv, 0.0f);
        size_t off = (size_t)(row0+i)*N + col;
        if (RES) vv += resid[off];
        if (OUTF32) ((float*)outp)[off] = vv;
        else        ((u16*)outp)[off] = f2bf(vv);
      }
    }
  }
}

// ---------------- flash attention (split-bf16 QK^T) ----------------
// grid: (SEQ/64, BATCH*NHEAD). 4 waves, each owns 16 q-rows. KBLK=64.
// All LDS tiles have 128B rows; swizzle: colByte ^= ((row&7)^((row>>3)&7))<<4.
__device__ __forceinline__ int swz128(int row, int colByte){
  return row*128 + (colByte ^ ((((row&7)^((row>>3)&7))&7)<<4));
}

__global__ __launch_bounds__(256) void attn_kernel(const float* __restrict__ qkv,
                                                   float* __restrict__ att){
  int bh = blockIdx.y;
  int b = bh >> 4, h = bh & 15;
  int t = threadIdx.x, l = t&63, w = t>>6;
  const int rowStride = 3*DMODEL;
  const float* qb = qkv + (size_t)b*SEQ*rowStride + h*DH;
  const float* kb = qb + DMODEL;
  const float* vb = qb + 2*DMODEL;
  int q0 = blockIdx.x*64 + w*16;

  short8 qh[2], ql[2];
  #pragma unroll
  for (int kc=0;kc<2;++kc){
    const float* qp = qb + (size_t)(q0 + (l&15))*rowStride + kc*32 + ((l>>4)<<3);
    float qv[8];
    *reinterpret_cast<float4*>(&qv[0]) = reinterpret_cast<const float4*>(qp)[0];
    *reinterpret_cast<float4*>(&qv[4]) = reinterpret_cast<const float4*>(qp)[1];
    split8(qv, qh[kc], ql[kc]);
  }

  __shared__ u16 Kh[64*64];
  __shared__ u16 Kl[64*64];
  __shared__ u16 Vt[64*64];
  __shared__ u16 Pl[4][16*64];
  char* KhB = (char*)Kh;
  char* KlB = (char*)Kl;
  char* VtB = (char*)Vt;
  char* PlB = (char*)&Pl[w][0];

  f32x4 o[4];
  #pragma unroll
  for (int d=0; d<4; ++d)
    #pragma unroll
    for (int i=0;i<4;++i) o[d][i] = 0.0f;
  float m_run[4], l_run[4];
  #pragma unroll
  for (int i=0;i<4;++i){ m_run[i] = -3.0e38f; l_run[i] = 0.0f; }

  for (int kt=0; kt<SEQ/64; ++kt){
    __syncthreads();
    // stage K hi/lo (swizzled) and V transposed bf16 (swizzled)
    #pragma unroll
    for (int i=0;i<2;++i){
      int idx = i*256 + t;
      int r = idx>>3, c8 = (idx&7)*8;
      {
        const float* kp = kb + (size_t)(kt*64 + r)*rowStride + c8;
        float kv[8];
        *reinterpret_cast<float4*>(&kv[0]) = reinterpret_cast<const float4*>(kp)[0];
        *reinterpret_cast<float4*>(&kv[4]) = reinterpret_cast<const float4*>(kp)[1];
        short8 hi, lo; split8(kv, hi, lo);
        *reinterpret_cast<short8*>(KhB + swz128(r, c8*2)) = hi;
        *reinterpret_cast<short8*>(KlB + swz128(r, c8*2)) = lo;
      }
      {
        const float* vp = vb + (size_t)(kt*64 + r)*rowStride + c8;
        float vv[8];
        *reinterpret_cast<float4*>(&vv[0]) = reinterpret_cast<const float4*>(vp)[0];
        *reinterpret_cast<float4*>(&vv[4]) = reinterpret_cast<const float4*>(vp)[1];
        #pragma unroll
        for (int j=0;j<8;++j)
          *reinterpret_cast<u16*>(VtB + swz128(c8+j, r*2)) = f2bf(vv[j]);
      }
    }
    __syncthreads();

    // QK^T (split: 3 MFMAs per chunk)
    f32x4 sc4[4];
    #pragma unroll
    for (int st=0; st<4; ++st){
      #pragma unroll
      for (int i=0;i<4;++i) sc4[st][i] = 0.0f;
      #pragma unroll
      for (int kc=0; kc<2; ++kc){
        int rr = st*16 + (l&15);
        int cb = (kc*32 + ((l>>4)<<3))*2;
        short8 kfh = *reinterpret_cast<const short8*>(KhB + swz128(rr, cb));
        short8 kfl = *reinterpret_cast<const short8*>(KlB + swz128(rr, cb));
        sc4[st] = __builtin_amdgcn_mfma_f32_16x16x32_bf16(qh[kc], kfh, sc4[st], 0,0,0);
        sc4[st] = __builtin_amdgcn_mfma_f32_16x16x32_bf16(qh[kc], kfl, sc4[st], 0,0,0);
        sc4[st] = __builtin_amdgcn_mfma_f32_16x16x32_bf16(ql[kc], kfh, sc4[st], 0,0,0);
      }
    }

    // online softmax (rows: (l>>4)*4+i, reduce across 16 lanes)
    float mt[4];
    #pragma unroll
    for (int i=0;i<4;++i)
      mt[i] = fmaxf(fmaxf(sc4[0][i], sc4[1][i]), fmaxf(sc4[2][i], sc4[3][i]));
    #pragma unroll
    for (int mk=1; mk<16; mk<<=1)
      #pragma unroll
      for (int i=0;i<4;++i) mt[i] = fmaxf(mt[i], __shfl_xor(mt[i], mk));

    float scl[4], rsum[4];
    u16 pb[4][4];
    #pragma unroll
    for (int i=0;i<4;++i){
      float mn = fmaxf(m_run[i], mt[i]);
      scl[i] = __expf(m_run[i] - mn);
      m_run[i] = mn;
      float sum = 0.0f;
      #pragma unroll
      for (int st=0; st<4; ++st){
        float p = __expf(sc4[st][i] - mn);
        sum += p;
        pb[st][i] = f2bf(p);
      }
      rsum[i] = sum;
    }
    #pragma unroll
    for (int mk=1; mk<16; mk<<=1)
      #pragma unroll
      for (int i=0;i<4;++i) rsum[i] += __shfl_xor(rsum[i], mk);
    #pragma unroll
    for (int i=0;i<4;++i) l_run[i] = l_run[i]*scl[i] + rsum[i];
    #pragma unroll
    for (int d=0; d<4; ++d)
      #pragma unroll
      for (int i=0;i<4;++i) o[d][i] *= scl[i];

    // write P (bf16) to per-wave LDS
    #pragma unroll
    for (int i=0;i<4;++i){
      int r = ((l>>4)<<2) + i;
      #pragma unroll
      for (int st=0; st<4; ++st)
        *reinterpret_cast<u16*>(PlB + swz128(r, (st*16 + (l&15))*2)) = pb[st][i];
    }
    __syncthreads();

    // PV
    #pragma unroll
    for (int kc=0; kc<2; ++kc){
      int pr = l&15;
      short8 pa = *reinterpret_cast<const short8*>(PlB + swz128(pr, (kc*32 + ((l>>4)<<3))*2));
      #pragma unroll
      for (int d=0; d<4; ++d){
        int vr = d*16 + (l&15);
        short8 vf = *reinterpret_cast<const short8*>(VtB + swz128(vr, (kc*32 + ((l>>4)<<3))*2));
        o[d] = __builtin_amdgcn_mfma_f32_16x16x32_bf16(pa, vf, o[d], 0,0,0);
      }
    }
  }

  #pragma unroll
  for (int i=0;i<4;++i){
    float inv = 1.0f / l_run[i];
    int row = b*SEQ + q0 + ((l>>4)<<2) + i;
    #pragma unroll
    for (int d=0; d<4; ++d)
      att[(size_t)row*DMODEL + h*DH + d*16 + (l&15)] = o[d][i] * inv;
  }
}

// ---------------- launch ----------------
extern "C" void kernel_launch(void* const* d_in, const int* in_sizes, int n_in,
                              void* d_out, int out_size, void* d_ws, size_t ws_size,
                              hipStream_t stream){
  (void)in_sizes; (void)n_in; (void)out_size; (void)ws_size;
  const float* x    = (const float*)d_in[0];
  const float* Wq   = (const float*)d_in[1];
  const float* Wk   = (const float*)d_in[2];
  const float* Wv   = (const float*)d_in[3];
  const float* W1   = (const float*)d_in[4];
  const float* b1   = (const float*)d_in[5];
  const float* W2   = (const float*)d_in[6];
  const float* b2   = (const float*)d_in[7];
  const float* ln1s = (const float*)d_in[8];
  const float* ln1b = (const float*)d_in[9];
  const float* ln2s = (const float*)d_in[10];
  const float* ln2b = (const float*)d_in[11];

  char* ws = (char*)d_ws;
  float* xn_f32  = (float*)ws;  ws += (size_t)NTOK*DMODEL*4;
  float* att_f32 = (float*)ws;  ws += (size_t)NTOK*DMODEL*4;
  float* xt_f32  = (float*)ws;  ws += (size_t)NTOK*DMODEL*4;
  float* qkv_f32 = (float*)ws;  ws += (size_t)NTOK*3*DMODEL*4;
  u16* xt_bf     = (u16*)ws;    ws += (size_t)NTOK*DMODEL*2;
  u16* h_bf      = (u16*)ws;    ws += (size_t)NTOK*DMODEL*2;
  u16* w1_bf     = (u16*)ws;    ws += (size_t)DMODEL*DMODEL*2;
  u16* w2_bf     = (u16*)ws;    ws += (size_t)DMODEL*DMODEL*2;

  const int nW = DMODEL*DMODEL;
  const int cvtBlocks = nW/4/256;
  cvt_f32_bf16<<<cvtBlocks, 256, 0, stream>>>(W1, w1_bf, nW);
  cvt_f32_bf16<<<cvtBlocks, 256, 0, stream>>>(W2, w2_bf, nW);

  ln_kernel<<<NTOK, 256, 0, stream>>>(x, nullptr, ln1s, ln1b, xn_f32, nullptr);

  gemm_qkv_split<<<dim3(3*DMODEL/128, NTOK/128), 256, 0, stream>>>(
      xn_f32, Wq, Wk, Wv, qkv_f32, NTOK, 3*DMODEL, DMODEL);

  attn_kernel<<<dim3(SEQ/64, BATCH*NHEAD), 256, 0, stream>>>(qkv_f32, att_f32);

  ln_kernel<<<NTOK, 256, 0, stream>>>(xn_f32, att_f32, ln2s, ln2b, xt_f32, xt_bf);

  gemm_bt<true,true,false,false><<<dim3(DMODEL/128, NTOK/128), 256, 0, stream>>>(
      xt_bf, w1_bf, b1, nullptr, h_bf, NTOK, DMODEL, DMODEL);

  gemm_bt<true,false,true,true><<<dim3(DMODEL/128, NTOK/128), 256, 0, stream>>>(
      h_bf, w2_bf, b2, xt_f32, d_out, NTOK, DMODEL, DMODEL);
}